// Round 9
// baseline (155.084 us; speedup 1.0000x reference)
//
#include <hip/hip_runtime.h>
#include <hip/hip_fp16.h>

// LightGCN propagation, CSR-by-destination formulation.
// N=100000 nodes, D=64 dims, E=1250000 edges (sizes read from in_sizes).
//
// R9 = R8 with the compile fix (__builtin_nontemporal_store needs a native
// vector type, not HIP's float4 class -> store via ext_vector_type(4) alias).
// R8 changes vs R7:
//  - bcnt layout transposed to [g][b]: k_bhist count writes and k_bscatter
//    cursor reads are now coalesced (was stride-1KB 4B accesses = ~50 MB of
//    hidden 64B-line traffic). Scan restructured: k_colprefix (thread-per-
//    bucket column prefix over chunks, coalesced) + k_btot_scan (single-block
//    scan of 1563 bucket totals -> bbase).
//  - k_z0 fused into k_bfinal (bucket block computes dinv then writes its 64
//    nodes' fp16 z0 rows).
//  - prop3 writes `out` with nontemporal stores (write-once stream).
// Props themselves unchanged: they sit at the L3 random-128B-gather ceiling
// (~5.7 TB/s effective); fp16 z is the smallest dtype inside error budget.

#define G 256        // edge-chunk blocks for hist/scatter
#define SH 6         // bucket = dst >> SH
#define BNODES 64    // nodes per bucket
#define WINV (1.0f / 32767.0f)

typedef float f4_native __attribute__((ext_vector_type(4)));

// ---------- P1: per-chunk bucket histogram (LDS, no device atomics) ----------
// bcnt[g*NB + b]  (transposed: coalesced writes)
__global__ void __launch_bounds__(256) k_bhist(const int* __restrict__ ei,
                                               int* __restrict__ bcnt, int NB, int E) {
    extern __shared__ unsigned int hist[];  // NB counters
    int g = blockIdx.x, t = threadIdx.x;
    for (int b = t; b < NB; b += 256) hist[b] = 0;
    __syncthreads();
    int chunk = (E + G - 1) / G;
    int lo = g * chunk;
    int hi = min(lo + chunk, E);
    for (int i = lo + t; i < hi; i += 256) {
        int d = ei[E + i];
        atomicAdd(&hist[d >> SH], 1u);
    }
    __syncthreads();
    for (int b = t; b < NB; b += 256) bcnt[(size_t)g * NB + b] = (int)hist[b];
}

// ---------- P2a: column prefix over chunks; thread per bucket (coalesced) ---
__global__ void k_colprefix(const int* __restrict__ bcnt, int* __restrict__ sc0,
                            int* __restrict__ btot, int NB) {
    int b = blockIdx.x * blockDim.x + threadIdx.x;
    if (b >= NB) return;
    int run = 0;
    #pragma unroll 8
    for (int g = 0; g < G; ++g) {
        int v = bcnt[(size_t)g * NB + b];
        sc0[(size_t)g * NB + b] = run;
        run += v;
    }
    btot[b] = run;
}

// ---------- P2b: single-block exclusive scan of NB bucket totals ----------
__global__ void __launch_bounds__(256) k_btot_scan(const int* __restrict__ btot,
                                                   int* __restrict__ bbase, int NB) {
    __shared__ int s[256];
    __shared__ int carry;
    int t = threadIdx.x;
    if (t == 0) carry = 0;
    __syncthreads();
    int ntile = (NB + 255) / 256;
    for (int tile = 0; tile < ntile; ++tile) {
        int i = tile * 256 + t;
        int v = (i < NB) ? btot[i] : 0;
        s[t] = v;
        __syncthreads();
        for (int off = 1; off < 256; off <<= 1) {
            int x = (t >= off) ? s[t - off] : 0;
            __syncthreads();
            s[t] += x;
            __syncthreads();
        }
        int incl = s[t];
        int c = carry;
        if (i < NB) bbase[i] = c + incl - v;  // exclusive
        __syncthreads();
        if (t == 255) carry = c + incl;
        __syncthreads();
    }
    if (t == 0) bbase[NB] = carry;  // == E
}

// ---------- P3: bucket-sorted scatter via LDS cursors ----------
__global__ void __launch_bounds__(256) k_bscatter(const int* __restrict__ ei,
                                                  const float* __restrict__ ea,
                                                  const int* __restrict__ sc0,
                                                  const int* __restrict__ bbase,
                                                  int2* __restrict__ ebuf, int NB, int E) {
    extern __shared__ unsigned int cur[];  // NB cursors
    int g = blockIdx.x, t = threadIdx.x;
    for (int b = t; b < NB; b += 256)
        cur[b] = (unsigned)(bbase[b] + sc0[(size_t)g * NB + b]);  // coalesced
    __syncthreads();
    int chunk = (E + G - 1) / G;
    int lo = g * chunk;
    int hi = min(lo + chunk, E);
    for (int i = lo + t; i < hi; i += 256) {
        int srcv = ei[i];
        int d = ei[E + i];
        float w = ea[i];
        unsigned pos = atomicAdd(&cur[d >> SH], 1u);
        int2 m;
        m.x = srcv | ((d & (BNODES - 1)) << 25);  // src < 2^17, dlow in bits 25..30
        m.y = __float_as_int(w);
        ebuf[pos] = m;
    }
}

// ---------- P4: per-bucket node sort -> meta(u32), row_start, dinv, z0 ------
__global__ void __launch_bounds__(256) k_bfinal(const int2* __restrict__ ebuf,
                                                const int* __restrict__ bbase,
                                                const float2* __restrict__ emb2,
                                                unsigned int* __restrict__ meta,
                                                int* __restrict__ row_start,
                                                float* __restrict__ dinv,
                                                __half2* __restrict__ z0,
                                                int NB, int N, int E) {
    __shared__ unsigned int hcnt[BNODES];
    __shared__ float hsum[BNODES];
    __shared__ unsigned int hoff[BNODES];
    __shared__ unsigned int cur[BNODES];
    __shared__ float sdv[BNODES];
    int b = blockIdx.x, t = threadIdx.x;
    if (t < BNODES) {
        hcnt[t] = 0;
        hsum[t] = 0.0f;
    }
    __syncthreads();
    int e0 = bbase[b];
    int e1 = bbase[b + 1];
    for (int i = e0 + t; i < e1; i += 256) {
        int2 m = ebuf[i];
        int dl = (m.x >> 25) & (BNODES - 1);
        atomicAdd(&hcnt[dl], 1u);
        atomicAdd(&hsum[dl], __int_as_float(m.y));
    }
    __syncthreads();
    if (t == 0) {
        unsigned r = 0;
        for (int k = 0; k < BNODES; ++k) {
            hoff[k] = r;
            r += hcnt[k];
        }
    }
    __syncthreads();
    if (t < BNODES) {
        cur[t] = hoff[t];
        float s = hsum[t];
        float dv = (s > 0.0f) ? rsqrtf(s) : 0.0f;
        sdv[t] = dv;
        int node = (b << SH) + t;
        if (node < N) {
            row_start[node] = e0 + (int)hoff[t];
            dinv[node] = dv;
        }
    }
    if (b == 0 && t == 0) row_start[N] = E;
    __syncthreads();
    // node-sorted meta with q15 weight
    for (int i = e0 + t; i < e1; i += 256) {
        int2 m = ebuf[i];
        int dl = (m.x >> 25) & (BNODES - 1);
        unsigned p = atomicAdd(&cur[dl], 1u);
        float w = __int_as_float(m.y);
        unsigned q = (unsigned)__float2int_rn(w * 32767.0f);
        q = min(q, 32767u);
        meta[e0 + (int)p] = (unsigned)(m.x & ((1 << 17) - 1)) | (q << 17);
    }
    // fused z0 = fp16(emb * dinv) for this bucket's 64 nodes (64 nodes x 32 float2)
    int base = b << SH;
    for (int idx = t; idx < BNODES * 32; idx += 256) {
        int node = idx >> 5;
        int gnode = base + node;
        if (gnode < N) {
            float s = sdv[node];
            float2 v = emb2[(size_t)gnode * 32 + (idx & 31)];
            z0[(size_t)gnode * 32 + (idx & 31)] = __floats2half2_rn(v.x * s, v.y * s);
        }
    }
}

union F2H {
    float2 f;
    __half2 h[2];
};

// ---------- propagation: x_new = dinv * sum(w * z[src]); z_new = dinv*x_new ----
// 16-lane group per destination node; lane l owns dims 4l..4l+3.
// MODE 0: write zout = dinv^2*acc.   MODE 1 (last layer, fused final):
//   out = 0.25*(emb + rd*z1 + rd*z2 + sd*acc), rd = 1/dinv.
template <int MODE>
__global__ void __launch_bounds__(256) k_prop(const float2* __restrict__ zin,
                                              const unsigned int* __restrict__ meta,
                                              const int* __restrict__ row_start,
                                              const float* __restrict__ dinv,
                                              float2* __restrict__ zout,
                                              const float4* __restrict__ emb,
                                              const float2* __restrict__ z1,
                                              const float2* __restrict__ z2,
                                              float4* __restrict__ out, int N) {
    int g = (blockIdx.x * 256 + threadIdx.x) >> 4;
    if (g >= N) return;
    int l = threadIdx.x & 15;
    int b = row_start[g];
    int e = row_start[g + 1];

    float4 acc = make_float4(0.f, 0.f, 0.f, 0.f);
    int i = b;
    for (; i + 8 <= e; i += 8) {
        unsigned mm[8];
        F2H uu[8];
        #pragma unroll
        for (int k = 0; k < 8; ++k) mm[k] = meta[i + k];
        #pragma unroll
        for (int k = 0; k < 8; ++k) uu[k].f = zin[(size_t)(mm[k] & 0x1FFFFu) * 16 + l];
        #pragma unroll
        for (int k = 0; k < 8; ++k) {
            float w = (float)(mm[k] >> 17) * WINV;
            float2 a = __half22float2(uu[k].h[0]), bb = __half22float2(uu[k].h[1]);
            acc.x = fmaf(a.x, w, acc.x);
            acc.y = fmaf(a.y, w, acc.y);
            acc.z = fmaf(bb.x, w, acc.z);
            acc.w = fmaf(bb.y, w, acc.w);
        }
    }
    for (; i + 4 <= e; i += 4) {
        unsigned mm[4];
        F2H uu[4];
        #pragma unroll
        for (int k = 0; k < 4; ++k) mm[k] = meta[i + k];
        #pragma unroll
        for (int k = 0; k < 4; ++k) uu[k].f = zin[(size_t)(mm[k] & 0x1FFFFu) * 16 + l];
        #pragma unroll
        for (int k = 0; k < 4; ++k) {
            float w = (float)(mm[k] >> 17) * WINV;
            float2 a = __half22float2(uu[k].h[0]), bb = __half22float2(uu[k].h[1]);
            acc.x = fmaf(a.x, w, acc.x);
            acc.y = fmaf(a.y, w, acc.y);
            acc.z = fmaf(bb.x, w, acc.z);
            acc.w = fmaf(bb.y, w, acc.w);
        }
    }
    for (; i < e; ++i) {
        unsigned m = meta[i];
        F2H u;
        u.f = zin[(size_t)(m & 0x1FFFFu) * 16 + l];
        float w = (float)(m >> 17) * WINV;
        float2 a = __half22float2(u.h[0]), bb = __half22float2(u.h[1]);
        acc.x = fmaf(a.x, w, acc.x);
        acc.y = fmaf(a.y, w, acc.y);
        acc.z = fmaf(bb.x, w, acc.z);
        acc.w = fmaf(bb.y, w, acc.w);
    }

    float sd = dinv[g];
    int o = g * 16 + l;
    if (MODE == 0) {
        float s2 = sd * sd;
        F2H u;
        u.h[0] = __floats2half2_rn(s2 * acc.x, s2 * acc.y);
        u.h[1] = __floats2half2_rn(s2 * acc.z, s2 * acc.w);
        zout[o] = u.f;
    } else {
        float rd = (sd > 0.0f) ? (1.0f / sd) : 0.0f;
        F2H u1, u2;
        u1.f = z1[o];
        u2.f = z2[o];
        float2 a1 = __half22float2(u1.h[0]), b1 = __half22float2(u1.h[1]);
        float2 a2 = __half22float2(u2.h[0]), b2 = __half22float2(u2.h[1]);
        float4 ev = emb[o];
        f4_native r;
        r.x = 0.25f * (ev.x + rd * (a1.x + a2.x) + sd * acc.x);
        r.y = 0.25f * (ev.y + rd * (a1.y + a2.y) + sd * acc.y);
        r.z = 0.25f * (ev.z + rd * (b1.x + b2.x) + sd * acc.z);
        r.w = 0.25f * (ev.w + rd * (b1.y + b2.y) + sd * acc.w);
        __builtin_nontemporal_store(r, reinterpret_cast<f4_native*>(&out[o]));
    }
}

static inline size_t align_up(size_t x, size_t a) { return (x + a - 1) & ~(a - 1); }

extern "C" void kernel_launch(void* const* d_in, const int* in_sizes, int n_in,
                              void* d_out, int out_size, void* d_ws, size_t ws_size,
                              hipStream_t stream) {
    const float* emb = (const float*)d_in[0];
    const float* ea  = (const float*)d_in[1];
    const int*   ei  = (const int*)d_in[2];
    float* out = (float*)d_out;

    const int D = 64;
    const int N = in_sizes[0] / D;
    const int E = in_sizes[1];

    const int NB = (N + BNODES - 1) / BNODES;   // 1563
    const int NS = NB * G;                      // 400128

    // workspace carve (all 256B-aligned)
    char* ws = (char*)d_ws;
    size_t off = 0;
    int* bcnt = (int*)(ws + off);           off = align_up(off + (size_t)NS * 4, 256);
    int* sc0 = (int*)(ws + off);            off = align_up(off + (size_t)NS * 4, 256);
    int* btot = (int*)(ws + off);           off = align_up(off + (size_t)NB * 4, 256);
    int* bbase = (int*)(ws + off);          off = align_up(off + (size_t)(NB + 1) * 4, 256);
    int* row_start = (int*)(ws + off);      off = align_up(off + (size_t)(N + 1) * 4, 256);
    float* dinv = (float*)(ws + off);       off = align_up(off + (size_t)N * 4, 256);
    int2* ebuf = (int2*)(ws + off);         off = align_up(off + (size_t)E * 8, 256);
    unsigned int* meta = (unsigned int*)(ws + off); off = align_up(off + (size_t)E * 4, 256);
    __half2* z0 = (__half2*)(ws + off);     off = align_up(off + (size_t)N * D * 2, 256);
    __half2* z1 = (__half2*)(ws + off);     off = align_up(off + (size_t)N * D * 2, 256);
    __half2* z2 = (__half2*)(ws + off);     off = align_up(off + (size_t)N * D * 2, 256);
    (void)ws_size;

    // ---- CSR build, atomic-free ----
    k_bhist<<<G, 256, NB * 4, stream>>>(ei, bcnt, NB, E);
    k_colprefix<<<(NB + 255) / 256, 256, 0, stream>>>(bcnt, sc0, btot, NB);
    k_btot_scan<<<1, 256, 0, stream>>>(btot, bbase, NB);
    k_bscatter<<<G, 256, NB * 4, stream>>>(ei, ea, sc0, bbase, ebuf, NB, E);
    k_bfinal<<<NB, 256, 0, stream>>>(ebuf, bbase, (const float2*)emb, meta, row_start,
                                     dinv, z0, NB, N, E);

    // ---- propagation ----
    int lb = (N * 16 + 255) / 256;
    k_prop<0><<<lb, 256, 0, stream>>>((const float2*)z0, meta, row_start, dinv,
                                      (float2*)z1, nullptr, nullptr, nullptr, nullptr, N);
    k_prop<0><<<lb, 256, 0, stream>>>((const float2*)z1, meta, row_start, dinv,
                                      (float2*)z2, nullptr, nullptr, nullptr, nullptr, N);
    k_prop<1><<<lb, 256, 0, stream>>>((const float2*)z2, meta, row_start, dinv,
                                      nullptr, (const float4*)emb, (const float2*)z1,
                                      (const float2*)z2, (float4*)out, N);
}

// Round 10
// 150.580 us; speedup vs baseline: 1.0299x; 1.0299x over previous
//
#include <hip/hip_runtime.h>
#include <hip/hip_fp16.h>

// LightGCN propagation, CSR-by-destination formulation.
// N=100000 nodes, D=64 dims, E=1250000 edges (sizes read from in_sizes).
//
// R10 changes vs R9:
//  - k_colprefix (1563 threads = 25 waves, remote-L2 latency-bound, ~12-15us)
//    replaced by a segmented scan: k_seg (NBx16 threads, segment partials),
//    k_segbase (thread/bucket scans 16 partials), k_btot_scan (unchanged),
//    k_sc0 (NBx16 threads write running prefixes). ~390 waves, latency-hidden.
//  - Nontemporal `out` store reverted to plain store (suspect #2 in the R9
//    regression: NT bypasses L2 write-combining).
// Kept from R8/R9: transposed bcnt [g][b] (coalesced bhist/bscatter), z0
// fused into k_bfinal, q15-packed 4B meta, fused final in prop3.

#define G 256        // edge-chunk blocks for hist/scatter
#define SH 6         // bucket = dst >> SH
#define BNODES 64    // nodes per bucket
#define NSEG 16      // scan segments over the G chunks
#define SEGC (G / NSEG)
#define WINV (1.0f / 32767.0f)

// ---------- P1: per-chunk bucket histogram (LDS, no device atomics) ----------
// bcnt[g*NB + b]  (transposed: coalesced writes)
__global__ void __launch_bounds__(256) k_bhist(const int* __restrict__ ei,
                                               int* __restrict__ bcnt, int NB, int E) {
    extern __shared__ unsigned int hist[];  // NB counters
    int g = blockIdx.x, t = threadIdx.x;
    for (int b = t; b < NB; b += 256) hist[b] = 0;
    __syncthreads();
    int chunk = (E + G - 1) / G;
    int lo = g * chunk;
    int hi = min(lo + chunk, E);
    for (int i = lo + t; i < hi; i += 256) {
        int d = ei[E + i];
        atomicAdd(&hist[d >> SH], 1u);
    }
    __syncthreads();
    for (int b = t; b < NB; b += 256) bcnt[(size_t)g * NB + b] = (int)hist[b];
}

// ---------- P2a: segment partials; thread = (s, b), b fastest (coalesced) ----
__global__ void k_seg(const int* __restrict__ bcnt, int* __restrict__ seg, int NB) {
    int tid = blockIdx.x * blockDim.x + threadIdx.x;
    if (tid >= NB * NSEG) return;
    int s = tid / NB;
    int b = tid - s * NB;
    int run = 0;
    #pragma unroll
    for (int j = 0; j < SEGC; ++j) run += bcnt[(size_t)(s * SEGC + j) * NB + b];
    seg[tid] = run;
}

// ---------- P2b: per-bucket scan of NSEG partials (in place) + btot ----------
__global__ void k_segbase(int* __restrict__ seg, int* __restrict__ btot, int NB) {
    int b = blockIdx.x * blockDim.x + threadIdx.x;
    if (b >= NB) return;
    int run = 0;
    #pragma unroll
    for (int s = 0; s < NSEG; ++s) {
        int v = seg[s * NB + b];
        seg[s * NB + b] = run;
        run += v;
    }
    btot[b] = run;
}

// ---------- P2c: single-block exclusive scan of NB bucket totals ----------
__global__ void __launch_bounds__(256) k_btot_scan(const int* __restrict__ btot,
                                                   int* __restrict__ bbase, int NB) {
    __shared__ int s[256];
    __shared__ int carry;
    int t = threadIdx.x;
    if (t == 0) carry = 0;
    __syncthreads();
    int ntile = (NB + 255) / 256;
    for (int tile = 0; tile < ntile; ++tile) {
        int i = tile * 256 + t;
        int v = (i < NB) ? btot[i] : 0;
        s[t] = v;
        __syncthreads();
        for (int off = 1; off < 256; off <<= 1) {
            int x = (t >= off) ? s[t - off] : 0;
            __syncthreads();
            s[t] += x;
            __syncthreads();
        }
        int incl = s[t];
        int c = carry;
        if (i < NB) bbase[i] = c + incl - v;  // exclusive
        __syncthreads();
        if (t == 255) carry = c + incl;
        __syncthreads();
    }
    if (t == 0) bbase[NB] = carry;  // == E
}

// ---------- P2d: write per-chunk bases sc0 (same tiling as k_seg) ----------
__global__ void k_sc0(const int* __restrict__ bcnt, const int* __restrict__ seg,
                      int* __restrict__ sc0, int NB) {
    int tid = blockIdx.x * blockDim.x + threadIdx.x;
    if (tid >= NB * NSEG) return;
    int s = tid / NB;
    int b = tid - s * NB;
    int run = seg[tid];
    #pragma unroll
    for (int j = 0; j < SEGC; ++j) {
        size_t idx = (size_t)(s * SEGC + j) * NB + b;
        sc0[idx] = run;
        run += bcnt[idx];
    }
}

// ---------- P3: bucket-sorted scatter via LDS cursors ----------
__global__ void __launch_bounds__(256) k_bscatter(const int* __restrict__ ei,
                                                  const float* __restrict__ ea,
                                                  const int* __restrict__ sc0,
                                                  const int* __restrict__ bbase,
                                                  int2* __restrict__ ebuf, int NB, int E) {
    extern __shared__ unsigned int cur[];  // NB cursors
    int g = blockIdx.x, t = threadIdx.x;
    for (int b = t; b < NB; b += 256)
        cur[b] = (unsigned)(bbase[b] + sc0[(size_t)g * NB + b]);  // coalesced
    __syncthreads();
    int chunk = (E + G - 1) / G;
    int lo = g * chunk;
    int hi = min(lo + chunk, E);
    for (int i = lo + t; i < hi; i += 256) {
        int srcv = ei[i];
        int d = ei[E + i];
        float w = ea[i];
        unsigned pos = atomicAdd(&cur[d >> SH], 1u);
        int2 m;
        m.x = srcv | ((d & (BNODES - 1)) << 25);  // src < 2^17, dlow in bits 25..30
        m.y = __float_as_int(w);
        ebuf[pos] = m;
    }
}

// ---------- P4: per-bucket node sort -> meta(u32), row_start, dinv, z0 ------
__global__ void __launch_bounds__(256) k_bfinal(const int2* __restrict__ ebuf,
                                                const int* __restrict__ bbase,
                                                const float2* __restrict__ emb2,
                                                unsigned int* __restrict__ meta,
                                                int* __restrict__ row_start,
                                                float* __restrict__ dinv,
                                                __half2* __restrict__ z0,
                                                int NB, int N, int E) {
    __shared__ unsigned int hcnt[BNODES];
    __shared__ float hsum[BNODES];
    __shared__ unsigned int hoff[BNODES];
    __shared__ unsigned int cur[BNODES];
    __shared__ float sdv[BNODES];
    int b = blockIdx.x, t = threadIdx.x;
    if (t < BNODES) {
        hcnt[t] = 0;
        hsum[t] = 0.0f;
    }
    __syncthreads();
    int e0 = bbase[b];
    int e1 = bbase[b + 1];
    for (int i = e0 + t; i < e1; i += 256) {
        int2 m = ebuf[i];
        int dl = (m.x >> 25) & (BNODES - 1);
        atomicAdd(&hcnt[dl], 1u);
        atomicAdd(&hsum[dl], __int_as_float(m.y));
    }
    __syncthreads();
    if (t == 0) {
        unsigned r = 0;
        for (int k = 0; k < BNODES; ++k) {
            hoff[k] = r;
            r += hcnt[k];
        }
    }
    __syncthreads();
    if (t < BNODES) {
        cur[t] = hoff[t];
        float s = hsum[t];
        float dv = (s > 0.0f) ? rsqrtf(s) : 0.0f;
        sdv[t] = dv;
        int node = (b << SH) + t;
        if (node < N) {
            row_start[node] = e0 + (int)hoff[t];
            dinv[node] = dv;
        }
    }
    if (b == 0 && t == 0) row_start[N] = E;
    __syncthreads();
    // node-sorted meta with q15 weight
    for (int i = e0 + t; i < e1; i += 256) {
        int2 m = ebuf[i];
        int dl = (m.x >> 25) & (BNODES - 1);
        unsigned p = atomicAdd(&cur[dl], 1u);
        float w = __int_as_float(m.y);
        unsigned q = (unsigned)__float2int_rn(w * 32767.0f);
        q = min(q, 32767u);
        meta[e0 + (int)p] = (unsigned)(m.x & ((1 << 17) - 1)) | (q << 17);
    }
    // fused z0 = fp16(emb * dinv) for this bucket's 64 nodes (64 nodes x 32 float2)
    int base = b << SH;
    for (int idx = t; idx < BNODES * 32; idx += 256) {
        int node = idx >> 5;
        int gnode = base + node;
        if (gnode < N) {
            float s = sdv[node];
            float2 v = emb2[(size_t)gnode * 32 + (idx & 31)];
            z0[(size_t)gnode * 32 + (idx & 31)] = __floats2half2_rn(v.x * s, v.y * s);
        }
    }
}

union F2H {
    float2 f;
    __half2 h[2];
};

// ---------- propagation: x_new = dinv * sum(w * z[src]); z_new = dinv*x_new ----
// 16-lane group per destination node; lane l owns dims 4l..4l+3.
// MODE 0: write zout = dinv^2*acc.   MODE 1 (last layer, fused final):
//   out = 0.25*(emb + rd*z1 + rd*z2 + sd*acc), rd = 1/dinv.
template <int MODE>
__global__ void __launch_bounds__(256) k_prop(const float2* __restrict__ zin,
                                              const unsigned int* __restrict__ meta,
                                              const int* __restrict__ row_start,
                                              const float* __restrict__ dinv,
                                              float2* __restrict__ zout,
                                              const float4* __restrict__ emb,
                                              const float2* __restrict__ z1,
                                              const float2* __restrict__ z2,
                                              float4* __restrict__ out, int N) {
    int g = (blockIdx.x * 256 + threadIdx.x) >> 4;
    if (g >= N) return;
    int l = threadIdx.x & 15;
    int b = row_start[g];
    int e = row_start[g + 1];

    float4 acc = make_float4(0.f, 0.f, 0.f, 0.f);
    int i = b;
    for (; i + 8 <= e; i += 8) {
        unsigned mm[8];
        F2H uu[8];
        #pragma unroll
        for (int k = 0; k < 8; ++k) mm[k] = meta[i + k];
        #pragma unroll
        for (int k = 0; k < 8; ++k) uu[k].f = zin[(size_t)(mm[k] & 0x1FFFFu) * 16 + l];
        #pragma unroll
        for (int k = 0; k < 8; ++k) {
            float w = (float)(mm[k] >> 17) * WINV;
            float2 a = __half22float2(uu[k].h[0]), bb = __half22float2(uu[k].h[1]);
            acc.x = fmaf(a.x, w, acc.x);
            acc.y = fmaf(a.y, w, acc.y);
            acc.z = fmaf(bb.x, w, acc.z);
            acc.w = fmaf(bb.y, w, acc.w);
        }
    }
    for (; i + 4 <= e; i += 4) {
        unsigned mm[4];
        F2H uu[4];
        #pragma unroll
        for (int k = 0; k < 4; ++k) mm[k] = meta[i + k];
        #pragma unroll
        for (int k = 0; k < 4; ++k) uu[k].f = zin[(size_t)(mm[k] & 0x1FFFFu) * 16 + l];
        #pragma unroll
        for (int k = 0; k < 4; ++k) {
            float w = (float)(mm[k] >> 17) * WINV;
            float2 a = __half22float2(uu[k].h[0]), bb = __half22float2(uu[k].h[1]);
            acc.x = fmaf(a.x, w, acc.x);
            acc.y = fmaf(a.y, w, acc.y);
            acc.z = fmaf(bb.x, w, acc.z);
            acc.w = fmaf(bb.y, w, acc.w);
        }
    }
    for (; i < e; ++i) {
        unsigned m = meta[i];
        F2H u;
        u.f = zin[(size_t)(m & 0x1FFFFu) * 16 + l];
        float w = (float)(m >> 17) * WINV;
        float2 a = __half22float2(u.h[0]), bb = __half22float2(u.h[1]);
        acc.x = fmaf(a.x, w, acc.x);
        acc.y = fmaf(a.y, w, acc.y);
        acc.z = fmaf(bb.x, w, acc.z);
        acc.w = fmaf(bb.y, w, acc.w);
    }

    float sd = dinv[g];
    int o = g * 16 + l;
    if (MODE == 0) {
        float s2 = sd * sd;
        F2H u;
        u.h[0] = __floats2half2_rn(s2 * acc.x, s2 * acc.y);
        u.h[1] = __floats2half2_rn(s2 * acc.z, s2 * acc.w);
        zout[o] = u.f;
    } else {
        float rd = (sd > 0.0f) ? (1.0f / sd) : 0.0f;
        F2H u1, u2;
        u1.f = z1[o];
        u2.f = z2[o];
        float2 a1 = __half22float2(u1.h[0]), b1 = __half22float2(u1.h[1]);
        float2 a2 = __half22float2(u2.h[0]), b2 = __half22float2(u2.h[1]);
        float4 ev = emb[o];
        float4 r;
        r.x = 0.25f * (ev.x + rd * (a1.x + a2.x) + sd * acc.x);
        r.y = 0.25f * (ev.y + rd * (a1.y + a2.y) + sd * acc.y);
        r.z = 0.25f * (ev.z + rd * (b1.x + b2.x) + sd * acc.z);
        r.w = 0.25f * (ev.w + rd * (b1.y + b2.y) + sd * acc.w);
        out[o] = r;
    }
}

static inline size_t align_up(size_t x, size_t a) { return (x + a - 1) & ~(a - 1); }

extern "C" void kernel_launch(void* const* d_in, const int* in_sizes, int n_in,
                              void* d_out, int out_size, void* d_ws, size_t ws_size,
                              hipStream_t stream) {
    const float* emb = (const float*)d_in[0];
    const float* ea  = (const float*)d_in[1];
    const int*   ei  = (const int*)d_in[2];
    float* out = (float*)d_out;

    const int D = 64;
    const int N = in_sizes[0] / D;
    const int E = in_sizes[1];

    const int NB = (N + BNODES - 1) / BNODES;   // 1563
    const int NS = NB * G;                      // 400128

    // workspace carve (all 256B-aligned)
    char* ws = (char*)d_ws;
    size_t off = 0;
    int* bcnt = (int*)(ws + off);           off = align_up(off + (size_t)NS * 4, 256);
    int* sc0 = (int*)(ws + off);            off = align_up(off + (size_t)NS * 4, 256);
    int* seg = (int*)(ws + off);            off = align_up(off + (size_t)NB * NSEG * 4, 256);
    int* btot = (int*)(ws + off);           off = align_up(off + (size_t)NB * 4, 256);
    int* bbase = (int*)(ws + off);          off = align_up(off + (size_t)(NB + 1) * 4, 256);
    int* row_start = (int*)(ws + off);      off = align_up(off + (size_t)(N + 1) * 4, 256);
    float* dinv = (float*)(ws + off);       off = align_up(off + (size_t)N * 4, 256);
    int2* ebuf = (int2*)(ws + off);         off = align_up(off + (size_t)E * 8, 256);
    unsigned int* meta = (unsigned int*)(ws + off); off = align_up(off + (size_t)E * 4, 256);
    __half2* z0 = (__half2*)(ws + off);     off = align_up(off + (size_t)N * D * 2, 256);
    __half2* z1 = (__half2*)(ws + off);     off = align_up(off + (size_t)N * D * 2, 256);
    __half2* z2 = (__half2*)(ws + off);     off = align_up(off + (size_t)N * D * 2, 256);
    (void)ws_size;

    // ---- CSR build, atomic-free ----
    k_bhist<<<G, 256, NB * 4, stream>>>(ei, bcnt, NB, E);
    int segblk = (NB * NSEG + 255) / 256;
    k_seg<<<segblk, 256, 0, stream>>>(bcnt, seg, NB);
    k_segbase<<<(NB + 255) / 256, 256, 0, stream>>>(seg, btot, NB);
    k_btot_scan<<<1, 256, 0, stream>>>(btot, bbase, NB);
    k_sc0<<<segblk, 256, 0, stream>>>(bcnt, seg, sc0, NB);
    k_bscatter<<<G, 256, NB * 4, stream>>>(ei, ea, sc0, bbase, ebuf, NB, E);
    k_bfinal<<<NB, 256, 0, stream>>>(ebuf, bbase, (const float2*)emb, meta, row_start,
                                     dinv, z0, NB, N, E);

    // ---- propagation ----
    int lb = (N * 16 + 255) / 256;
    k_prop<0><<<lb, 256, 0, stream>>>((const float2*)z0, meta, row_start, dinv,
                                      (float2*)z1, nullptr, nullptr, nullptr, nullptr, N);
    k_prop<0><<<lb, 256, 0, stream>>>((const float2*)z1, meta, row_start, dinv,
                                      (float2*)z2, nullptr, nullptr, nullptr, nullptr, N);
    k_prop<1><<<lb, 256, 0, stream>>>((const float2*)z2, meta, row_start, dinv,
                                      nullptr, (const float4*)emb, (const float2*)z1,
                                      (const float2*)z2, (float4*)out, N);
}

// Round 11
// 147.819 us; speedup vs baseline: 1.0492x; 1.0187x over previous
//
#include <hip/hip_runtime.h>
#include <hip/hip_fp16.h>

// LightGCN propagation, CSR-by-destination formulation.
// N=100000 nodes, D=64 dims, E=1250000 edges (sizes read from in_sizes).
//
// R11 changes vs R10 (build collapsed 7 launches -> 3 + tiny memset; props
// unchanged): R8-R10 showed the scan micro-kernels are LAUNCH-GAP-bound,
// not BW-bound.
//  - SH=9: 512-node buckets, NB=196 (<=256). Bucket totals (gcur) built by
//    50K returning device atomics inside k_hist (one per block x bucket;
//    ~2.4us at the measured ~21 G op/s cap -- the cap hurt at 1.25M ops,
//    not at 50K). chunkbase[g][b] = returned offset.
//  - k_bscatter / k_bfinal each re-derive the 196-bucket exclusive scan of
//    gcur in LDS (8 Hillis-Steele steps, ~1us, redundant per block) --
//    deletes k_seg/k_segbase/k_btot_scan/k_sc0 and their gaps.
//  - k_bfinal: 512 threads, parallel 512-node LDS scan (was serial t==0).
//    z0 (fp16 emb*dinv) stays fused here.
// Props identical to R10: q15-packed 4B meta, fp16 z gathers, fused final.

#define G 256        // edge-chunk blocks for hist/scatter
#define SH 9         // bucket = dst >> SH
#define BNODES 512   // nodes per bucket
#define WINV (1.0f / 32767.0f)

// ---------- P1: per-chunk LDS histogram + chunk-base reservation ----------
// gcur[b]: running bucket total (device atomic); chunkbase[g*NB+b] = old.
__global__ void __launch_bounds__(256) k_hist(const int* __restrict__ ei,
                                              unsigned int* __restrict__ gcur,
                                              int* __restrict__ chunkbase,
                                              int NB, int E) {
    extern __shared__ unsigned int hist[];  // NB counters
    int g = blockIdx.x, t = threadIdx.x;
    for (int b = t; b < NB; b += 256) hist[b] = 0;
    __syncthreads();
    int chunk = (E + G - 1) / G;
    int lo = g * chunk;
    int hi = min(lo + chunk, E);
    for (int i = lo + t; i < hi; i += 256) {
        int d = ei[E + i];
        atomicAdd(&hist[d >> SH], 1u);
    }
    __syncthreads();
    for (int b = t; b < NB; b += 256) {
        unsigned h = hist[b];
        unsigned base = atomicAdd(&gcur[b], h);  // 50K total returning atomics
        chunkbase[(size_t)g * NB + b] = (int)base;
    }
}

// ---------- P2: bucket-sorted scatter; bbase re-derived in-block ----------
__global__ void __launch_bounds__(256) k_bscatter(const int* __restrict__ ei,
                                                  const float* __restrict__ ea,
                                                  const unsigned int* __restrict__ gcur,
                                                  const int* __restrict__ chunkbase,
                                                  int2* __restrict__ ebuf, int NB, int E) {
    extern __shared__ unsigned int cur[];  // NB cursors
    __shared__ int tot[256];               // inclusive scan of bucket totals
    int g = blockIdx.x, t = threadIdx.x;
    // exclusive scan of gcur[0..NB) (NB <= 256)
    tot[t] = (t < NB) ? (int)gcur[t] : 0;
    __syncthreads();
    for (int off = 1; off < 256; off <<= 1) {
        int x = (t >= off) ? tot[t - off] : 0;
        __syncthreads();
        tot[t] += x;
        __syncthreads();
    }
    for (int b = t; b < NB; b += 256)
        cur[b] = (unsigned)(tot[b] - (int)gcur[b] + chunkbase[(size_t)g * NB + b]);
    __syncthreads();
    int chunk = (E + G - 1) / G;
    int lo = g * chunk;
    int hi = min(lo + chunk, E);
    for (int i = lo + t; i < hi; i += 256) {
        int srcv = ei[i];
        int d = ei[E + i];
        float w = ea[i];
        unsigned pos = atomicAdd(&cur[d >> SH], 1u);
        int2 m;
        m.x = srcv | ((d & (BNODES - 1)) << 17);  // src < 2^17, dlow in bits 17..25
        m.y = __float_as_int(w);
        ebuf[pos] = m;
    }
}

// ---------- P3: per-bucket node sort -> meta(u32), row_start, dinv, z0 ------
__global__ void __launch_bounds__(512) k_bfinal(const int2* __restrict__ ebuf,
                                                const unsigned int* __restrict__ gcur,
                                                const float2* __restrict__ emb2,
                                                unsigned int* __restrict__ meta,
                                                int* __restrict__ row_start,
                                                float* __restrict__ dinv,
                                                __half2* __restrict__ z0,
                                                int NB, int N, int E) {
    __shared__ int tot[256];
    __shared__ unsigned int hcnt[BNODES];
    __shared__ float hsum[BNODES];
    __shared__ int sbuf[BNODES];
    __shared__ unsigned int cur[BNODES];
    __shared__ float sdv[BNODES];
    int b = blockIdx.x, t = threadIdx.x;

    // exclusive bucket-base scan (NB <= 256), done by threads 0..255
    if (t < 256) tot[t] = (t < NB) ? (int)gcur[t] : 0;
    __syncthreads();
    for (int off = 1; off < 256; off <<= 1) {
        int x = (t < 256 && t >= off) ? tot[t - off] : 0;
        __syncthreads();
        if (t < 256) tot[t] += x;
        __syncthreads();
    }
    int e1 = tot[b];                   // inclusive
    int e0 = e1 - (int)gcur[b];        // exclusive

    hcnt[t] = 0;
    hsum[t] = 0.0f;
    __syncthreads();
    for (int i = e0 + t; i < e1; i += 512) {
        int2 m = ebuf[i];
        int dl = (m.x >> 17) & (BNODES - 1);
        atomicAdd(&hcnt[dl], 1u);
        atomicAdd(&hsum[dl], __int_as_float(m.y));
    }
    __syncthreads();
    // parallel inclusive scan of hcnt over 512
    sbuf[t] = (int)hcnt[t];
    __syncthreads();
    for (int off = 1; off < BNODES; off <<= 1) {
        int x = (t >= off) ? sbuf[t - off] : 0;
        __syncthreads();
        sbuf[t] += x;
        __syncthreads();
    }
    int excl = sbuf[t] - (int)hcnt[t];
    cur[t] = (unsigned)excl;
    float s = hsum[t];
    float dv = (s > 0.0f) ? rsqrtf(s) : 0.0f;
    sdv[t] = dv;
    int node = (b << SH) + t;
    if (node < N) {
        row_start[node] = e0 + excl;
        dinv[node] = dv;
    }
    if (b == 0 && t == 0) row_start[N] = E;
    __syncthreads();
    // node-sorted meta with q15 weight
    for (int i = e0 + t; i < e1; i += 512) {
        int2 m = ebuf[i];
        int dl = (m.x >> 17) & (BNODES - 1);
        unsigned p = atomicAdd(&cur[dl], 1u);
        float w = __int_as_float(m.y);
        unsigned q = (unsigned)__float2int_rn(w * 32767.0f);
        q = min(q, 32767u);
        meta[e0 + (int)p] = (unsigned)(m.x & ((1 << 17) - 1)) | (q << 17);
    }
    // fused z0 = fp16(emb * dinv): 512 nodes x 32 half2, coalesced
    int base = b << SH;
    for (int idx = t; idx < BNODES * 32; idx += 512) {
        int nd = idx >> 5;
        int gnode = base + nd;
        if (gnode < N) {
            float sc = sdv[nd];
            float2 v = emb2[(size_t)gnode * 32 + (idx & 31)];
            z0[(size_t)gnode * 32 + (idx & 31)] = __floats2half2_rn(v.x * sc, v.y * sc);
        }
    }
}

union F2H {
    float2 f;
    __half2 h[2];
};

// ---------- propagation: x_new = dinv * sum(w * z[src]); z_new = dinv*x_new ----
// 16-lane group per destination node; lane l owns dims 4l..4l+3.
// MODE 0: write zout = dinv^2*acc.   MODE 1 (last layer, fused final):
//   out = 0.25*(emb + rd*z1 + rd*z2 + sd*acc), rd = 1/dinv.
template <int MODE>
__global__ void __launch_bounds__(256) k_prop(const float2* __restrict__ zin,
                                              const unsigned int* __restrict__ meta,
                                              const int* __restrict__ row_start,
                                              const float* __restrict__ dinv,
                                              float2* __restrict__ zout,
                                              const float4* __restrict__ emb,
                                              const float2* __restrict__ z1,
                                              const float2* __restrict__ z2,
                                              float4* __restrict__ out, int N) {
    int g = (blockIdx.x * 256 + threadIdx.x) >> 4;
    if (g >= N) return;
    int l = threadIdx.x & 15;
    int b = row_start[g];
    int e = row_start[g + 1];

    float4 acc = make_float4(0.f, 0.f, 0.f, 0.f);
    int i = b;
    for (; i + 8 <= e; i += 8) {
        unsigned mm[8];
        F2H uu[8];
        #pragma unroll
        for (int k = 0; k < 8; ++k) mm[k] = meta[i + k];
        #pragma unroll
        for (int k = 0; k < 8; ++k) uu[k].f = zin[(size_t)(mm[k] & 0x1FFFFu) * 16 + l];
        #pragma unroll
        for (int k = 0; k < 8; ++k) {
            float w = (float)(mm[k] >> 17) * WINV;
            float2 a = __half22float2(uu[k].h[0]), bb = __half22float2(uu[k].h[1]);
            acc.x = fmaf(a.x, w, acc.x);
            acc.y = fmaf(a.y, w, acc.y);
            acc.z = fmaf(bb.x, w, acc.z);
            acc.w = fmaf(bb.y, w, acc.w);
        }
    }
    for (; i + 4 <= e; i += 4) {
        unsigned mm[4];
        F2H uu[4];
        #pragma unroll
        for (int k = 0; k < 4; ++k) mm[k] = meta[i + k];
        #pragma unroll
        for (int k = 0; k < 4; ++k) uu[k].f = zin[(size_t)(mm[k] & 0x1FFFFu) * 16 + l];
        #pragma unroll
        for (int k = 0; k < 4; ++k) {
            float w = (float)(mm[k] >> 17) * WINV;
            float2 a = __half22float2(uu[k].h[0]), bb = __half22float2(uu[k].h[1]);
            acc.x = fmaf(a.x, w, acc.x);
            acc.y = fmaf(a.y, w, acc.y);
            acc.z = fmaf(bb.x, w, acc.z);
            acc.w = fmaf(bb.y, w, acc.w);
        }
    }
    for (; i < e; ++i) {
        unsigned m = meta[i];
        F2H u;
        u.f = zin[(size_t)(m & 0x1FFFFu) * 16 + l];
        float w = (float)(m >> 17) * WINV;
        float2 a = __half22float2(u.h[0]), bb = __half22float2(u.h[1]);
        acc.x = fmaf(a.x, w, acc.x);
        acc.y = fmaf(a.y, w, acc.y);
        acc.z = fmaf(bb.x, w, acc.z);
        acc.w = fmaf(bb.y, w, acc.w);
    }

    float sd = dinv[g];
    int o = g * 16 + l;
    if (MODE == 0) {
        float s2 = sd * sd;
        F2H u;
        u.h[0] = __floats2half2_rn(s2 * acc.x, s2 * acc.y);
        u.h[1] = __floats2half2_rn(s2 * acc.z, s2 * acc.w);
        zout[o] = u.f;
    } else {
        float rd = (sd > 0.0f) ? (1.0f / sd) : 0.0f;
        F2H u1, u2;
        u1.f = z1[o];
        u2.f = z2[o];
        float2 a1 = __half22float2(u1.h[0]), b1 = __half22float2(u1.h[1]);
        float2 a2 = __half22float2(u2.h[0]), b2 = __half22float2(u2.h[1]);
        float4 ev = emb[o];
        float4 r;
        r.x = 0.25f * (ev.x + rd * (a1.x + a2.x) + sd * acc.x);
        r.y = 0.25f * (ev.y + rd * (a1.y + a2.y) + sd * acc.y);
        r.z = 0.25f * (ev.z + rd * (b1.x + b2.x) + sd * acc.z);
        r.w = 0.25f * (ev.w + rd * (b1.y + b2.y) + sd * acc.w);
        out[o] = r;
    }
}

static inline size_t align_up(size_t x, size_t a) { return (x + a - 1) & ~(a - 1); }

extern "C" void kernel_launch(void* const* d_in, const int* in_sizes, int n_in,
                              void* d_out, int out_size, void* d_ws, size_t ws_size,
                              hipStream_t stream) {
    const float* emb = (const float*)d_in[0];
    const float* ea  = (const float*)d_in[1];
    const int*   ei  = (const int*)d_in[2];
    float* out = (float*)d_out;

    const int D = 64;
    const int N = in_sizes[0] / D;
    const int E = in_sizes[1];

    const int NB = (N + BNODES - 1) / BNODES;   // 196 for N=100000 (must be <=256)

    // workspace carve (all 256B-aligned)
    char* ws = (char*)d_ws;
    size_t off = 0;
    unsigned int* gcur = (unsigned int*)(ws + off);
                                            off = align_up(off + (size_t)NB * 4, 256);
    int* chunkbase = (int*)(ws + off);      off = align_up(off + (size_t)G * NB * 4, 256);
    int* row_start = (int*)(ws + off);      off = align_up(off + (size_t)(N + 1) * 4, 256);
    float* dinv = (float*)(ws + off);       off = align_up(off + (size_t)N * 4, 256);
    int2* ebuf = (int2*)(ws + off);         off = align_up(off + (size_t)E * 8, 256);
    unsigned int* meta = (unsigned int*)(ws + off); off = align_up(off + (size_t)E * 4, 256);
    __half2* z0 = (__half2*)(ws + off);     off = align_up(off + (size_t)N * D * 2, 256);
    __half2* z1 = (__half2*)(ws + off);     off = align_up(off + (size_t)N * D * 2, 256);
    __half2* z2 = (__half2*)(ws + off);     off = align_up(off + (size_t)N * D * 2, 256);
    (void)ws_size;

    // ---- CSR build: 3 kernels + tiny memset ----
    hipMemsetAsync(gcur, 0, (size_t)NB * 4, stream);
    k_hist<<<G, 256, NB * 4, stream>>>(ei, gcur, chunkbase, NB, E);
    k_bscatter<<<G, 256, NB * 4, stream>>>(ei, ea, gcur, chunkbase, ebuf, NB, E);
    k_bfinal<<<NB, 512, 0, stream>>>(ebuf, gcur, (const float2*)emb, meta, row_start,
                                     dinv, z0, NB, N, E);

    // ---- propagation ----
    int lb = (N * 16 + 255) / 256;
    k_prop<0><<<lb, 256, 0, stream>>>((const float2*)z0, meta, row_start, dinv,
                                      (float2*)z1, nullptr, nullptr, nullptr, nullptr, N);
    k_prop<0><<<lb, 256, 0, stream>>>((const float2*)z1, meta, row_start, dinv,
                                      (float2*)z2, nullptr, nullptr, nullptr, nullptr, N);
    k_prop<1><<<lb, 256, 0, stream>>>((const float2*)z2, meta, row_start, dinv,
                                      nullptr, (const float4*)emb, (const float2*)z1,
                                      (const float2*)z2, (float4*)out, N);
}

// Round 12
// 142.828 us; speedup vs baseline: 1.0858x; 1.0349x over previous
//
#include <hip/hip_runtime.h>
#include <hip/hip_fp16.h>

// LightGCN propagation, CSR-by-destination formulation.
// N=100000 nodes, D=64 dims, E=1250000 edges (sizes read from in_sizes).
//
// R12 changes vs R11:
//  - k_bfinal: removed the float LDS atomic (hsum). R11's 44us k_bfinal had
//    the fp32-CAS signature (R2's pathology in LDS): hipcc without
//    -munsafe-fp-atomics lowers float atomicAdd to a CAS retry loop even for
//    __shared__. Degree sum is now accumulated as q15 integers (native
//    ds_add_u32): hq[dl] += q in the scatter pass; deg = hq * (1/32767).
//    Quantization adds <=1.5e-5/edge to deg -- absmax budget has 3.7x room.
//  - All LDS atomics now native u32 (count pass: 1/edge; scatter: 2/edge).
// Everything else identical to R11 (3-kernel build, SH=9, fused z0, q15 meta,
// fp16 z props, fused final in prop3).

#define G 256        // edge-chunk blocks for hist/scatter
#define SH 9         // bucket = dst >> SH
#define BNODES 512   // nodes per bucket
#define WINV (1.0f / 32767.0f)

// ---------- P1: per-chunk LDS histogram + chunk-base reservation ----------
// gcur[b]: running bucket total (device atomic); chunkbase[g*NB+b] = old.
__global__ void __launch_bounds__(256) k_hist(const int* __restrict__ ei,
                                              unsigned int* __restrict__ gcur,
                                              int* __restrict__ chunkbase,
                                              int NB, int E) {
    extern __shared__ unsigned int hist[];  // NB counters
    int g = blockIdx.x, t = threadIdx.x;
    for (int b = t; b < NB; b += 256) hist[b] = 0;
    __syncthreads();
    int chunk = (E + G - 1) / G;
    int lo = g * chunk;
    int hi = min(lo + chunk, E);
    for (int i = lo + t; i < hi; i += 256) {
        int d = ei[E + i];
        atomicAdd(&hist[d >> SH], 1u);
    }
    __syncthreads();
    for (int b = t; b < NB; b += 256) {
        unsigned h = hist[b];
        unsigned base = atomicAdd(&gcur[b], h);  // 50K total returning atomics
        chunkbase[(size_t)g * NB + b] = (int)base;
    }
}

// ---------- P2: bucket-sorted scatter; bbase re-derived in-block ----------
__global__ void __launch_bounds__(256) k_bscatter(const int* __restrict__ ei,
                                                  const float* __restrict__ ea,
                                                  const unsigned int* __restrict__ gcur,
                                                  const int* __restrict__ chunkbase,
                                                  int2* __restrict__ ebuf, int NB, int E) {
    extern __shared__ unsigned int cur[];  // NB cursors
    __shared__ int tot[256];               // inclusive scan of bucket totals
    int g = blockIdx.x, t = threadIdx.x;
    // exclusive scan of gcur[0..NB) (NB <= 256)
    tot[t] = (t < NB) ? (int)gcur[t] : 0;
    __syncthreads();
    for (int off = 1; off < 256; off <<= 1) {
        int x = (t >= off) ? tot[t - off] : 0;
        __syncthreads();
        tot[t] += x;
        __syncthreads();
    }
    for (int b = t; b < NB; b += 256)
        cur[b] = (unsigned)(tot[b] - (int)gcur[b] + chunkbase[(size_t)g * NB + b]);
    __syncthreads();
    int chunk = (E + G - 1) / G;
    int lo = g * chunk;
    int hi = min(lo + chunk, E);
    for (int i = lo + t; i < hi; i += 256) {
        int srcv = ei[i];
        int d = ei[E + i];
        float w = ea[i];
        unsigned pos = atomicAdd(&cur[d >> SH], 1u);
        int2 m;
        m.x = srcv | ((d & (BNODES - 1)) << 17);  // src < 2^17, dlow in bits 17..25
        m.y = __float_as_int(w);
        ebuf[pos] = m;
    }
}

// ---------- P3: per-bucket node sort -> meta(u32), row_start, dinv, z0 ------
// All LDS atomics native u32; degree accumulated as q15 integer sum.
__global__ void __launch_bounds__(512) k_bfinal(const int2* __restrict__ ebuf,
                                                const unsigned int* __restrict__ gcur,
                                                const float2* __restrict__ emb2,
                                                unsigned int* __restrict__ meta,
                                                int* __restrict__ row_start,
                                                float* __restrict__ dinv,
                                                __half2* __restrict__ z0,
                                                int NB, int N, int E) {
    __shared__ int tot[256];
    __shared__ unsigned int hcnt[BNODES];
    __shared__ int sbuf[BNODES];
    __shared__ unsigned int cur[BNODES];
    __shared__ unsigned int hq[BNODES];
    __shared__ float sdv[BNODES];
    int b = blockIdx.x, t = threadIdx.x;

    // exclusive bucket-base scan (NB <= 256), done by threads 0..255
    if (t < 256) tot[t] = (t < NB) ? (int)gcur[t] : 0;
    __syncthreads();
    for (int off = 1; off < 256; off <<= 1) {
        int x = (t < 256 && t >= off) ? tot[t - off] : 0;
        __syncthreads();
        if (t < 256) tot[t] += x;
        __syncthreads();
    }
    int e1 = tot[b];                   // inclusive
    int e0 = e1 - (int)gcur[b];        // exclusive

    hcnt[t] = 0;
    hq[t] = 0;
    __syncthreads();
    // pass 1: counts only (native ds_add_u32)
    for (int i = e0 + t; i < e1; i += 512) {
        int2 m = ebuf[i];
        atomicAdd(&hcnt[(m.x >> 17) & (BNODES - 1)], 1u);
    }
    __syncthreads();
    // parallel inclusive scan of hcnt over 512
    sbuf[t] = (int)hcnt[t];
    __syncthreads();
    for (int off = 1; off < BNODES; off <<= 1) {
        int x = (t >= off) ? sbuf[t - off] : 0;
        __syncthreads();
        sbuf[t] += x;
        __syncthreads();
    }
    int excl = sbuf[t] - (int)hcnt[t];
    cur[t] = (unsigned)excl;
    int node = (b << SH) + t;
    if (node < N) row_start[node] = e0 + excl;
    if (b == 0 && t == 0) row_start[N] = E;
    __syncthreads();
    // pass 2: node-sorted meta with q15 weight + q15 degree sum (native u32)
    for (int i = e0 + t; i < e1; i += 512) {
        int2 m = ebuf[i];
        int dl = (m.x >> 17) & (BNODES - 1);
        unsigned p = atomicAdd(&cur[dl], 1u);
        float w = __int_as_float(m.y);
        unsigned q = (unsigned)__float2int_rn(w * 32767.0f);
        q = min(q, 32767u);
        atomicAdd(&hq[dl], q);
        meta[e0 + (int)p] = (unsigned)(m.x & ((1 << 17) - 1)) | (q << 17);
    }
    __syncthreads();
    float s = (float)hq[t] * WINV;
    float dv = (s > 0.0f) ? rsqrtf(s) : 0.0f;
    sdv[t] = dv;
    if (node < N) dinv[node] = dv;
    __syncthreads();
    // fused z0 = fp16(emb * dinv): 512 nodes x 32 half2, coalesced
    int base = b << SH;
    for (int idx = t; idx < BNODES * 32; idx += 512) {
        int nd = idx >> 5;
        int gnode = base + nd;
        if (gnode < N) {
            float sc = sdv[nd];
            float2 v = emb2[(size_t)gnode * 32 + (idx & 31)];
            z0[(size_t)gnode * 32 + (idx & 31)] = __floats2half2_rn(v.x * sc, v.y * sc);
        }
    }
}

union F2H {
    float2 f;
    __half2 h[2];
};

// ---------- propagation: x_new = dinv * sum(w * z[src]); z_new = dinv*x_new ----
// 16-lane group per destination node; lane l owns dims 4l..4l+3.
// MODE 0: write zout = dinv^2*acc.   MODE 1 (last layer, fused final):
//   out = 0.25*(emb + rd*z1 + rd*z2 + sd*acc), rd = 1/dinv.
template <int MODE>
__global__ void __launch_bounds__(256) k_prop(const float2* __restrict__ zin,
                                              const unsigned int* __restrict__ meta,
                                              const int* __restrict__ row_start,
                                              const float* __restrict__ dinv,
                                              float2* __restrict__ zout,
                                              const float4* __restrict__ emb,
                                              const float2* __restrict__ z1,
                                              const float2* __restrict__ z2,
                                              float4* __restrict__ out, int N) {
    int g = (blockIdx.x * 256 + threadIdx.x) >> 4;
    if (g >= N) return;
    int l = threadIdx.x & 15;
    int b = row_start[g];
    int e = row_start[g + 1];

    float4 acc = make_float4(0.f, 0.f, 0.f, 0.f);
    int i = b;
    for (; i + 8 <= e; i += 8) {
        unsigned mm[8];
        F2H uu[8];
        #pragma unroll
        for (int k = 0; k < 8; ++k) mm[k] = meta[i + k];
        #pragma unroll
        for (int k = 0; k < 8; ++k) uu[k].f = zin[(size_t)(mm[k] & 0x1FFFFu) * 16 + l];
        #pragma unroll
        for (int k = 0; k < 8; ++k) {
            float w = (float)(mm[k] >> 17) * WINV;
            float2 a = __half22float2(uu[k].h[0]), bb = __half22float2(uu[k].h[1]);
            acc.x = fmaf(a.x, w, acc.x);
            acc.y = fmaf(a.y, w, acc.y);
            acc.z = fmaf(bb.x, w, acc.z);
            acc.w = fmaf(bb.y, w, acc.w);
        }
    }
    for (; i + 4 <= e; i += 4) {
        unsigned mm[4];
        F2H uu[4];
        #pragma unroll
        for (int k = 0; k < 4; ++k) mm[k] = meta[i + k];
        #pragma unroll
        for (int k = 0; k < 4; ++k) uu[k].f = zin[(size_t)(mm[k] & 0x1FFFFu) * 16 + l];
        #pragma unroll
        for (int k = 0; k < 4; ++k) {
            float w = (float)(mm[k] >> 17) * WINV;
            float2 a = __half22float2(uu[k].h[0]), bb = __half22float2(uu[k].h[1]);
            acc.x = fmaf(a.x, w, acc.x);
            acc.y = fmaf(a.y, w, acc.y);
            acc.z = fmaf(bb.x, w, acc.z);
            acc.w = fmaf(bb.y, w, acc.w);
        }
    }
    for (; i < e; ++i) {
        unsigned m = meta[i];
        F2H u;
        u.f = zin[(size_t)(m & 0x1FFFFu) * 16 + l];
        float w = (float)(m >> 17) * WINV;
        float2 a = __half22float2(u.h[0]), bb = __half22float2(u.h[1]);
        acc.x = fmaf(a.x, w, acc.x);
        acc.y = fmaf(a.y, w, acc.y);
        acc.z = fmaf(bb.x, w, acc.z);
        acc.w = fmaf(bb.y, w, acc.w);
    }

    float sd = dinv[g];
    int o = g * 16 + l;
    if (MODE == 0) {
        float s2 = sd * sd;
        F2H u;
        u.h[0] = __floats2half2_rn(s2 * acc.x, s2 * acc.y);
        u.h[1] = __floats2half2_rn(s2 * acc.z, s2 * acc.w);
        zout[o] = u.f;
    } else {
        float rd = (sd > 0.0f) ? (1.0f / sd) : 0.0f;
        F2H u1, u2;
        u1.f = z1[o];
        u2.f = z2[o];
        float2 a1 = __half22float2(u1.h[0]), b1 = __half22float2(u1.h[1]);
        float2 a2 = __half22float2(u2.h[0]), b2 = __half22float2(u2.h[1]);
        float4 ev = emb[o];
        float4 r;
        r.x = 0.25f * (ev.x + rd * (a1.x + a2.x) + sd * acc.x);
        r.y = 0.25f * (ev.y + rd * (a1.y + a2.y) + sd * acc.y);
        r.z = 0.25f * (ev.z + rd * (b1.x + b2.x) + sd * acc.z);
        r.w = 0.25f * (ev.w + rd * (b1.y + b2.y) + sd * acc.w);
        out[o] = r;
    }
}

static inline size_t align_up(size_t x, size_t a) { return (x + a - 1) & ~(a - 1); }

extern "C" void kernel_launch(void* const* d_in, const int* in_sizes, int n_in,
                              void* d_out, int out_size, void* d_ws, size_t ws_size,
                              hipStream_t stream) {
    const float* emb = (const float*)d_in[0];
    const float* ea  = (const float*)d_in[1];
    const int*   ei  = (const int*)d_in[2];
    float* out = (float*)d_out;

    const int D = 64;
    const int N = in_sizes[0] / D;
    const int E = in_sizes[1];

    const int NB = (N + BNODES - 1) / BNODES;   // 196 for N=100000 (must be <=256)

    // workspace carve (all 256B-aligned)
    char* ws = (char*)d_ws;
    size_t off = 0;
    unsigned int* gcur = (unsigned int*)(ws + off);
                                            off = align_up(off + (size_t)NB * 4, 256);
    int* chunkbase = (int*)(ws + off);      off = align_up(off + (size_t)G * NB * 4, 256);
    int* row_start = (int*)(ws + off);      off = align_up(off + (size_t)(N + 1) * 4, 256);
    float* dinv = (float*)(ws + off);       off = align_up(off + (size_t)N * 4, 256);
    int2* ebuf = (int2*)(ws + off);         off = align_up(off + (size_t)E * 8, 256);
    unsigned int* meta = (unsigned int*)(ws + off); off = align_up(off + (size_t)E * 4, 256);
    __half2* z0 = (__half2*)(ws + off);     off = align_up(off + (size_t)N * D * 2, 256);
    __half2* z1 = (__half2*)(ws + off);     off = align_up(off + (size_t)N * D * 2, 256);
    __half2* z2 = (__half2*)(ws + off);     off = align_up(off + (size_t)N * D * 2, 256);
    (void)ws_size;

    // ---- CSR build: 3 kernels + tiny memset ----
    hipMemsetAsync(gcur, 0, (size_t)NB * 4, stream);
    k_hist<<<G, 256, NB * 4, stream>>>(ei, gcur, chunkbase, NB, E);
    k_bscatter<<<G, 256, NB * 4, stream>>>(ei, ea, gcur, chunkbase, ebuf, NB, E);
    k_bfinal<<<NB, 512, 0, stream>>>(ebuf, gcur, (const float2*)emb, meta, row_start,
                                     dinv, z0, NB, N, E);

    // ---- propagation ----
    int lb = (N * 16 + 255) / 256;
    k_prop<0><<<lb, 256, 0, stream>>>((const float2*)z0, meta, row_start, dinv,
                                      (float2*)z1, nullptr, nullptr, nullptr, nullptr, N);
    k_prop<0><<<lb, 256, 0, stream>>>((const float2*)z1, meta, row_start, dinv,
                                      (float2*)z2, nullptr, nullptr, nullptr, nullptr, N);
    k_prop<1><<<lb, 256, 0, stream>>>((const float2*)z2, meta, row_start, dinv,
                                      nullptr, (const float4*)emb, (const float2*)z1,
                                      (const float2*)z2, (float4*)out, N);
}

// Round 13
// 139.634 us; speedup vs baseline: 1.1106x; 1.0229x over previous
//
#include <hip/hip_runtime.h>
#include <hip/hip_fp16.h>

// LightGCN propagation, CSR-by-destination formulation.
// N=100000 nodes, D=64 dims, E=1250000 edges (sizes read from in_sizes).
//
// R13 changes vs R12 (k_bfinal was still ~38us: 196 blocks = 0.76/CU, 12%
// occupancy, two global-latency passes per block -> latency-chain bound):
//  - SH=8: 256-node buckets, NB=391 -> 2x blocks, half the per-block path.
//    (gcur returning atomics 50K->100K = +2.4us at the measured ~21G op/s
//    cap, hidden inside k_hist.)
//  - k_bfinal stages its ebuf slice in LDS (CAP=6144 edges, 48KB; uniform
//    dst gives ~3200+-57/bucket so fast path always taken; block-uniform
//    fallback to the two-global-pass path preserves correctness for any
//    input). ebuf is read from global ONCE; count+scatter passes run on LDS.
//  - hq (q15 degree sum) accumulated in pass 1; scatter pass is cur+++write.
// Everything else identical to R12.

#define G 256        // edge-chunk blocks for hist/scatter
#define SH 8         // bucket = dst >> SH
#define BNODES 256   // nodes per bucket
#define CAP 6144     // max staged edges per bucket (48KB LDS)
#define WINV (1.0f / 32767.0f)

// ---------- P1: per-chunk LDS histogram + chunk-base reservation ----------
__global__ void __launch_bounds__(256) k_hist(const int* __restrict__ ei,
                                              unsigned int* __restrict__ gcur,
                                              int* __restrict__ chunkbase,
                                              int NB, int E) {
    extern __shared__ unsigned int hist[];  // NB counters
    int g = blockIdx.x, t = threadIdx.x;
    for (int b = t; b < NB; b += 256) hist[b] = 0;
    __syncthreads();
    int chunk = (E + G - 1) / G;
    int lo = g * chunk;
    int hi = min(lo + chunk, E);
    for (int i = lo + t; i < hi; i += 256) {
        int d = ei[E + i];
        atomicAdd(&hist[d >> SH], 1u);
    }
    __syncthreads();
    for (int b = t; b < NB; b += 256) {
        unsigned h = hist[b];
        unsigned base = atomicAdd(&gcur[b], h);  // 100K returning atomics total
        chunkbase[(size_t)g * NB + b] = (int)base;
    }
}

// ---------- P2: bucket-sorted scatter; bucket bases re-derived in-block -----
__global__ void __launch_bounds__(512) k_bscatter(const int* __restrict__ ei,
                                                  const float* __restrict__ ea,
                                                  const unsigned int* __restrict__ gcur,
                                                  const int* __restrict__ chunkbase,
                                                  int2* __restrict__ ebuf, int NB, int E) {
    __shared__ int tot[512];
    extern __shared__ unsigned int cur[];  // NB cursors
    int g = blockIdx.x, t = threadIdx.x;
    // inclusive scan of gcur over 512 slots (NB <= 512)
    tot[t] = (t < NB) ? (int)gcur[t] : 0;
    __syncthreads();
    for (int off = 1; off < 512; off <<= 1) {
        int x = (t >= off) ? tot[t - off] : 0;
        __syncthreads();
        tot[t] += x;
        __syncthreads();
    }
    for (int b = t; b < NB; b += 512)
        cur[b] = (unsigned)(tot[b] - (int)gcur[b] + chunkbase[(size_t)g * NB + b]);
    __syncthreads();
    int chunk = (E + G - 1) / G;
    int lo = g * chunk;
    int hi = min(lo + chunk, E);
    for (int i = lo + t; i < hi; i += 512) {
        int srcv = ei[i];
        int d = ei[E + i];
        float w = ea[i];
        unsigned pos = atomicAdd(&cur[d >> SH], 1u);
        int2 m;
        m.x = srcv | ((d & (BNODES - 1)) << 17);  // src < 2^17, dlow bits 17..24
        m.y = __float_as_int(w);
        ebuf[pos] = m;
    }
}

// ---------- P3: per-bucket node sort -> meta(u32), row_start, dinv, z0 ------
__global__ void __launch_bounds__(512) k_bfinal(const int2* __restrict__ ebuf,
                                                const unsigned int* __restrict__ gcur,
                                                const float2* __restrict__ emb2,
                                                unsigned int* __restrict__ meta,
                                                int* __restrict__ row_start,
                                                float* __restrict__ dinv,
                                                __half2* __restrict__ z0,
                                                int NB, int N, int E) {
    __shared__ int tot[512];
    __shared__ int2 estage[CAP];
    __shared__ unsigned int hcnt[BNODES];
    __shared__ int sbuf[BNODES];
    __shared__ unsigned int cur2[BNODES];
    __shared__ unsigned int hq[BNODES];
    __shared__ float sdv[BNODES];
    int b = blockIdx.x, t = threadIdx.x;

    // inclusive scan of gcur over 512 slots -> bucket edge range [e0, e1)
    tot[t] = (t < NB) ? (int)gcur[t] : 0;
    __syncthreads();
    for (int off = 1; off < 512; off <<= 1) {
        int x = (t >= off) ? tot[t - off] : 0;
        __syncthreads();
        tot[t] += x;
        __syncthreads();
    }
    int e1 = tot[b];
    int e0 = e1 - (int)gcur[b];
    int cnt = e1 - e0;

    if (t < BNODES) {
        hcnt[t] = 0;
        hq[t] = 0;
    }
    __syncthreads();

    if (cnt <= CAP) {
        // ---- fast path: single global read of ebuf, all passes on LDS ----
        for (int i = t; i < cnt; i += 512) estage[i] = ebuf[e0 + i];
        __syncthreads();
        for (int i = t; i < cnt; i += 512) {
            int2 m = estage[i];
            int dl = (m.x >> 17) & (BNODES - 1);
            float w = __int_as_float(m.y);
            unsigned q = (unsigned)__float2int_rn(w * 32767.0f);
            q = min(q, 32767u);
            atomicAdd(&hcnt[dl], 1u);
            atomicAdd(&hq[dl], q);
        }
        __syncthreads();
        if (t < BNODES) sbuf[t] = (int)hcnt[t];
        __syncthreads();
        for (int off = 1; off < BNODES; off <<= 1) {
            int x = (t < BNODES && t >= off) ? sbuf[t - off] : 0;
            __syncthreads();
            if (t < BNODES) sbuf[t] += x;
            __syncthreads();
        }
        int node = (b << SH) + t;
        if (t < BNODES) {
            int excl = sbuf[t] - (int)hcnt[t];
            cur2[t] = (unsigned)excl;
            float s = (float)hq[t] * WINV;
            float dv = (s > 0.0f) ? rsqrtf(s) : 0.0f;
            sdv[t] = dv;
            if (node < N) {
                row_start[node] = e0 + excl;
                dinv[node] = dv;
            }
        }
        __syncthreads();
        for (int i = t; i < cnt; i += 512) {
            int2 m = estage[i];
            int dl = (m.x >> 17) & (BNODES - 1);
            unsigned p = atomicAdd(&cur2[dl], 1u);
            float w = __int_as_float(m.y);
            unsigned q = (unsigned)__float2int_rn(w * 32767.0f);
            q = min(q, 32767u);
            meta[e0 + (int)p] = (unsigned)(m.x & ((1 << 17) - 1)) | (q << 17);
        }
    } else {
        // ---- fallback (block-uniform branch): two global passes ----
        for (int i = e0 + t; i < e1; i += 512) {
            int2 m = ebuf[i];
            int dl = (m.x >> 17) & (BNODES - 1);
            float w = __int_as_float(m.y);
            unsigned q = (unsigned)__float2int_rn(w * 32767.0f);
            q = min(q, 32767u);
            atomicAdd(&hcnt[dl], 1u);
            atomicAdd(&hq[dl], q);
        }
        __syncthreads();
        if (t < BNODES) sbuf[t] = (int)hcnt[t];
        __syncthreads();
        for (int off = 1; off < BNODES; off <<= 1) {
            int x = (t < BNODES && t >= off) ? sbuf[t - off] : 0;
            __syncthreads();
            if (t < BNODES) sbuf[t] += x;
            __syncthreads();
        }
        int node = (b << SH) + t;
        if (t < BNODES) {
            int excl = sbuf[t] - (int)hcnt[t];
            cur2[t] = (unsigned)excl;
            float s = (float)hq[t] * WINV;
            float dv = (s > 0.0f) ? rsqrtf(s) : 0.0f;
            sdv[t] = dv;
            if (node < N) {
                row_start[node] = e0 + excl;
                dinv[node] = dv;
            }
        }
        __syncthreads();
        for (int i = e0 + t; i < e1; i += 512) {
            int2 m = ebuf[i];
            int dl = (m.x >> 17) & (BNODES - 1);
            unsigned p = atomicAdd(&cur2[dl], 1u);
            float w = __int_as_float(m.y);
            unsigned q = (unsigned)__float2int_rn(w * 32767.0f);
            q = min(q, 32767u);
            meta[e0 + (int)p] = (unsigned)(m.x & ((1 << 17) - 1)) | (q << 17);
        }
    }
    if (b == 0 && t == 0) row_start[N] = E;
    __syncthreads();
    // fused z0 = fp16(emb * dinv): 256 nodes x 32 half2, coalesced
    int base = b << SH;
    for (int idx = t; idx < BNODES * 32; idx += 512) {
        int nd = idx >> 5;
        int gnode = base + nd;
        if (gnode < N) {
            float sc = sdv[nd];
            float2 v = emb2[(size_t)gnode * 32 + (idx & 31)];
            z0[(size_t)gnode * 32 + (idx & 31)] = __floats2half2_rn(v.x * sc, v.y * sc);
        }
    }
}

union F2H {
    float2 f;
    __half2 h[2];
};

// ---------- propagation: x_new = dinv * sum(w * z[src]); z_new = dinv*x_new ----
// 16-lane group per destination node; lane l owns dims 4l..4l+3.
// MODE 0: write zout = dinv^2*acc.   MODE 1 (last layer, fused final):
//   out = 0.25*(emb + rd*z1 + rd*z2 + sd*acc), rd = 1/dinv.
template <int MODE>
__global__ void __launch_bounds__(256) k_prop(const float2* __restrict__ zin,
                                              const unsigned int* __restrict__ meta,
                                              const int* __restrict__ row_start,
                                              const float* __restrict__ dinv,
                                              float2* __restrict__ zout,
                                              const float4* __restrict__ emb,
                                              const float2* __restrict__ z1,
                                              const float2* __restrict__ z2,
                                              float4* __restrict__ out, int N) {
    int g = (blockIdx.x * 256 + threadIdx.x) >> 4;
    if (g >= N) return;
    int l = threadIdx.x & 15;
    int b = row_start[g];
    int e = row_start[g + 1];

    float4 acc = make_float4(0.f, 0.f, 0.f, 0.f);
    int i = b;
    for (; i + 8 <= e; i += 8) {
        unsigned mm[8];
        F2H uu[8];
        #pragma unroll
        for (int k = 0; k < 8; ++k) mm[k] = meta[i + k];
        #pragma unroll
        for (int k = 0; k < 8; ++k) uu[k].f = zin[(size_t)(mm[k] & 0x1FFFFu) * 16 + l];
        #pragma unroll
        for (int k = 0; k < 8; ++k) {
            float w = (float)(mm[k] >> 17) * WINV;
            float2 a = __half22float2(uu[k].h[0]), bb = __half22float2(uu[k].h[1]);
            acc.x = fmaf(a.x, w, acc.x);
            acc.y = fmaf(a.y, w, acc.y);
            acc.z = fmaf(bb.x, w, acc.z);
            acc.w = fmaf(bb.y, w, acc.w);
        }
    }
    for (; i + 4 <= e; i += 4) {
        unsigned mm[4];
        F2H uu[4];
        #pragma unroll
        for (int k = 0; k < 4; ++k) mm[k] = meta[i + k];
        #pragma unroll
        for (int k = 0; k < 4; ++k) uu[k].f = zin[(size_t)(mm[k] & 0x1FFFFu) * 16 + l];
        #pragma unroll
        for (int k = 0; k < 4; ++k) {
            float w = (float)(mm[k] >> 17) * WINV;
            float2 a = __half22float2(uu[k].h[0]), bb = __half22float2(uu[k].h[1]);
            acc.x = fmaf(a.x, w, acc.x);
            acc.y = fmaf(a.y, w, acc.y);
            acc.z = fmaf(bb.x, w, acc.z);
            acc.w = fmaf(bb.y, w, acc.w);
        }
    }
    for (; i < e; ++i) {
        unsigned m = meta[i];
        F2H u;
        u.f = zin[(size_t)(m & 0x1FFFFu) * 16 + l];
        float w = (float)(m >> 17) * WINV;
        float2 a = __half22float2(u.h[0]), bb = __half22float2(u.h[1]);
        acc.x = fmaf(a.x, w, acc.x);
        acc.y = fmaf(a.y, w, acc.y);
        acc.z = fmaf(bb.x, w, acc.z);
        acc.w = fmaf(bb.y, w, acc.w);
    }

    float sd = dinv[g];
    int o = g * 16 + l;
    if (MODE == 0) {
        float s2 = sd * sd;
        F2H u;
        u.h[0] = __floats2half2_rn(s2 * acc.x, s2 * acc.y);
        u.h[1] = __floats2half2_rn(s2 * acc.z, s2 * acc.w);
        zout[o] = u.f;
    } else {
        float rd = (sd > 0.0f) ? (1.0f / sd) : 0.0f;
        F2H u1, u2;
        u1.f = z1[o];
        u2.f = z2[o];
        float2 a1 = __half22float2(u1.h[0]), b1 = __half22float2(u1.h[1]);
        float2 a2 = __half22float2(u2.h[0]), b2 = __half22float2(u2.h[1]);
        float4 ev = emb[o];
        float4 r;
        r.x = 0.25f * (ev.x + rd * (a1.x + a2.x) + sd * acc.x);
        r.y = 0.25f * (ev.y + rd * (a1.y + a2.y) + sd * acc.y);
        r.z = 0.25f * (ev.z + rd * (b1.x + b2.x) + sd * acc.z);
        r.w = 0.25f * (ev.w + rd * (b1.y + b2.y) + sd * acc.w);
        out[o] = r;
    }
}

static inline size_t align_up(size_t x, size_t a) { return (x + a - 1) & ~(a - 1); }

extern "C" void kernel_launch(void* const* d_in, const int* in_sizes, int n_in,
                              void* d_out, int out_size, void* d_ws, size_t ws_size,
                              hipStream_t stream) {
    const float* emb = (const float*)d_in[0];
    const float* ea  = (const float*)d_in[1];
    const int*   ei  = (const int*)d_in[2];
    float* out = (float*)d_out;

    const int D = 64;
    const int N = in_sizes[0] / D;
    const int E = in_sizes[1];

    const int NB = (N + BNODES - 1) / BNODES;   // 391 for N=100000 (must be <=512)

    // workspace carve (all 256B-aligned)
    char* ws = (char*)d_ws;
    size_t off = 0;
    unsigned int* gcur = (unsigned int*)(ws + off);
                                            off = align_up(off + (size_t)NB * 4, 256);
    int* chunkbase = (int*)(ws + off);      off = align_up(off + (size_t)G * NB * 4, 256);
    int* row_start = (int*)(ws + off);      off = align_up(off + (size_t)(N + 1) * 4, 256);
    float* dinv = (float*)(ws + off);       off = align_up(off + (size_t)N * 4, 256);
    int2* ebuf = (int2*)(ws + off);         off = align_up(off + (size_t)E * 8, 256);
    unsigned int* meta = (unsigned int*)(ws + off); off = align_up(off + (size_t)E * 4, 256);
    __half2* z0 = (__half2*)(ws + off);     off = align_up(off + (size_t)N * D * 2, 256);
    __half2* z1 = (__half2*)(ws + off);     off = align_up(off + (size_t)N * D * 2, 256);
    __half2* z2 = (__half2*)(ws + off);     off = align_up(off + (size_t)N * D * 2, 256);
    (void)ws_size;

    // ---- CSR build: 3 kernels + tiny memset ----
    hipMemsetAsync(gcur, 0, (size_t)NB * 4, stream);
    k_hist<<<G, 256, NB * 4, stream>>>(ei, gcur, chunkbase, NB, E);
    k_bscatter<<<G, 512, NB * 4, stream>>>(ei, ea, gcur, chunkbase, ebuf, NB, E);
    k_bfinal<<<NB, 512, 0, stream>>>(ebuf, gcur, (const float2*)emb, meta, row_start,
                                     dinv, z0, NB, N, E);

    // ---- propagation ----
    int lb = (N * 16 + 255) / 256;
    k_prop<0><<<lb, 256, 0, stream>>>((const float2*)z0, meta, row_start, dinv,
                                      (float2*)z1, nullptr, nullptr, nullptr, nullptr, N);
    k_prop<0><<<lb, 256, 0, stream>>>((const float2*)z1, meta, row_start, dinv,
                                      (float2*)z2, nullptr, nullptr, nullptr, nullptr, N);
    k_prop<1><<<lb, 256, 0, stream>>>((const float2*)z2, meta, row_start, dinv,
                                      nullptr, (const float4*)emb, (const float2*)z1,
                                      (const float2*)z2, (float4*)out, N);
}